// Round 11
// baseline (174.809 us; speedup 1.0000x reference)
//
#include <hip/hip_runtime.h>
#include <math.h>

// ---- static config (mirrors reference) ----
#define BB 16
#define AA 3
#define NCC 80
#define WW 76
#define MM 32
#define CELLS_PER_IMG (AA * WW * WW)          // 17328
#define NDECODE (BB * CELLS_PER_IMG * 85)     // 23,566,080
#define NCELLS (BB * CELLS_PER_IMG)           // 277,248
#define N4 (NDECODE / 4)                      // 5,891,520 float4s (N4 % 64 == 0)

typedef float vfloat4 __attribute__((ext_vector_type(4)));

__constant__ float c_anchor[9][2] = {
    {10.f,13.f},{16.f,30.f},{33.f,23.f},{30.f,61.f},{62.f,45.f},
    {59.f,119.f},{116.f,90.f},{156.f,198.f},{373.f,326.f}};

#define LOG2E 1.4426950408889634f

__device__ __forceinline__ float fast_sigmoid(float x) {
    return __builtin_amdgcn_rcpf(1.0f + __builtin_amdgcn_exp2f(-x * LOG2E));
}

__device__ __forceinline__ vfloat4 sig4(vfloat4 v) {
    vfloat4 o;
    o.x = fast_sigmoid(v.x);
    o.y = fast_sigmoid(v.y);
    o.z = fast_sigmoid(v.z);
    o.w = fast_sigmoid(v.w);
    return o;
}

// Fix the box-channel values inside this lane's float4 (registers only — the
// single NT stream store writes them; no second store to dec ever).
// Bit-identical math to the passing R1/R6/R7/R9 kernels.
__device__ __forceinline__ void fix_chunk(unsigned i4, const vfloat4 v, vfloat4& o) {
    unsigned b = i4 * 4u;
    unsigned cell = (b + 3u) / 85u;           // largest cell with 85*cell <= b+3
    int s = (int)(cell * 85u) - (int)b;       // window start rel. to b, in (-85, 3]
    if (s >= -3) {                            // chunk intersects a box window
        unsigned t  = cell / 76u;
        unsigned gi = cell - t * 76u;         // cell % 76
        unsigned t2 = t / 76u;
        unsigned gj = t - t2 * 76u;           // (cell/76) % 76
        unsigned a  = t2 % 3u;                // anchor index
        float aw = (a == 0u) ? 1.25f  : ((a == 1u) ? 2.0f  : 4.125f); // {10,16,33}*0.125
        float ah = (a == 0u) ? 1.625f : ((a == 1u) ? 3.75f : 2.875f); // {13,30,23}*0.125
        float q0 = (float)gi, q1 = (float)gj;
        float raw[4] = {v.x, v.y, v.z, v.w};
        float sg[4]  = {o.x, o.y, o.z, o.w};
        float res[4] = {o.x, o.y, o.z, o.w};
#pragma unroll
        for (int j = 0; j < 4; ++j) {
            int k = j - s;                    // channel index if inside window
            if ((unsigned)k < 4u) {
                float e    = __builtin_amdgcn_exp2f(raw[j] * LOG2E);
                float addq = (k == 0) ? q0 : q1;
                float an   = (k == 2) ? aw : ah;
                float val  = (k < 2) ? (sg[j] + addq) : (e * an);
                res[j] = val;
            }
        }
        o.x = res[0]; o.y = res[1]; o.z = res[2]; o.w = res[3];
    }
}

// ---------------------------------------------------------------------------
// Kernel 1: decode + FUSED noobj (R9 structure, PASSED at 173.3us) with ONE
// output-neutral change: the tail's 4 pred-gather dwords are issued together
// with the 4 stream loads (clamped in-span addresses) instead of after the
// NT stores — 8 loads in flight/wave, tail gather latency hidden under the
// stream compute. Pure read reorder; all writes identical to R9.
//   - R10 retrospective: the 8-wide retile + 2-lane tail FAILED the
//     post-timing poison/replay check with no identifiable indexing bug;
//     reverted wholesale. Do not re-attempt without isolating.
//   - NT on the 94 MB dec stream: VERIFIED (R1-R7 ledger) — cached dirty dec
//     lines slow the harness poison fills 6.8 -> 5.5 TB/s. dec is written
//     ONLY by the NT stream stores.
//   - Tail (R9): 4 lanes per cell (lanes 0..51), 8 IoUs each, 2-step
//     __shfl_xor max (exact for non-NaN); sub==0 writes noobj/obj (cached
//     scattered dwords — harmless to fills, R1/R7 evidence).
// ---------------------------------------------------------------------------
__global__ __launch_bounds__(256) void decode_kernel(const vfloat4* __restrict__ in,
                                                     vfloat4* __restrict__ out,
                                                     const float* __restrict__ pred,
                                                     const float* __restrict__ gt,
                                                     float* __restrict__ noobj,
                                                     float* __restrict__ obj) {
    // ---- stage GT xyxy for the (<=2) images this block can touch ----
    __shared__ float4 sbox[2 * MM];
    unsigned span_blk = blockIdx.x * 4096u;           // block's float span start
    unsigned cblk0    = (span_blk + 84u) / 85u;       // first cell owned by block
    unsigned bi0      = cblk0 / (unsigned)CELLS_PER_IMG;
    if (threadIdx.x < 64u) {
        unsigned m  = threadIdx.x & 31u;
        unsigned bi = bi0 + (threadIdx.x >> 5);
        if (bi < (unsigned)BB) {
            const float* g = gt + (size_t)(bi * MM + m) * 6;
            float cx = g[1], cy = g[2], gw = g[3], gh = g[4];
            sbox[threadIdx.x] = make_float4((cx - gw * 0.5f) * 608.0f,
                                            (cy - gh * 0.5f) * 608.0f,
                                            (cx + gw * 0.5f) * 608.0f,
                                            (cy + gh * 0.5f) * 608.0f);
        }
    }
    __syncthreads();

    unsigned tid  = blockIdx.x * 256u + threadIdx.x;
    unsigned wave = tid >> 6;
    unsigned lane = tid & 63u;
    unsigned i0 = wave * 256u + lane;       // wave-tiled: 1KB contiguous per instr
    unsigned i1 = i0 + 64u;
    unsigned i2 = i0 + 128u;
    unsigned i3 = i0 + 192u;
    const unsigned last = N4 - 1u;

    // clamped unconditional loads -> 4 independent stream loads in flight
    vfloat4 v0 = in[i0 < last ? i0 : last];
    vfloat4 v1 = in[i1 < last ? i1 : last];
    vfloat4 v2 = in[i2 < last ? i2 : last];
    vfloat4 v3 = in[i3 < last ? i3 : last];

    // ---- EARLY tail gather (rides with the stream loads; read-only) ----
    unsigned span = wave * 1024u;
    unsigned c0 = (span + 84u) / 85u;         // first cell with 85*c >= span
    unsigned j   = lane >> 2;                 // cell slot 0..15 (13 used)
    unsigned sub = lane & 3u;                 // GT quarter 0..3
    unsigned c  = c0 + j;
    unsigned wstart = c * 85u;                // window start (float index)
    bool tvalid = (j < 13u) && (wstart < span + 1024u) && (c < (unsigned)NCELLS);
    unsigned cg = c0 + (j < 13u ? j : 12u);   // clamp to wave's own windows
    if (cg > (unsigned)(NCELLS - 1)) cg = (unsigned)(NCELLS - 1);
    const float* tp = pred + (size_t)cg * 85u;  // 16B window, lines L1-resident
    float t0 = tp[0], t1 = tp[1], t2v = tp[2], t3v = tp[3];

    bool p0 = i0 < N4, p1 = i1 < N4, p2 = i2 < N4, p3 = i3 < N4;  // wave-uniform

    vfloat4 o0 = sig4(v0);
    vfloat4 o1 = sig4(v1);
    vfloat4 o2 = sig4(v2);
    vfloat4 o3 = sig4(v3);

    if (p0) fix_chunk(i0, v0, o0);
    if (p1) fix_chunk(i1, v1, o1);
    if (p2) fix_chunk(i2, v2, o2);
    if (p3) fix_chunk(i3, v3, o3);

    if (p0) __builtin_nontemporal_store(o0, &out[i0]);
    if (p1) __builtin_nontemporal_store(o1, &out[i1]);
    if (p2) __builtin_nontemporal_store(o2, &out[i2]);
    if (p3) __builtin_nontemporal_store(o3, &out[i3]);

    // ---- fused per-cell noobj: 4 lanes per cell, lanes 0..51 (R9) ----
    if (tvalid) {
        unsigned tq  = c / 76u;
        unsigned gi  = c - tq * 76u;          // cell % 76
        unsigned tq2 = tq / 76u;
        unsigned gj  = tq - tq2 * 76u;        // (cell/76) % 76
        unsigned a   = tq2 % 3u;
        float aw = (a == 0u) ? 1.25f  : ((a == 1u) ? 2.0f  : 4.125f);
        float ah = (a == 0u) ? 1.625f : ((a == 1u) ? 3.75f : 2.875f);
        float px = fast_sigmoid(t0) + (float)gi;
        float py = fast_sigmoid(t1) + (float)gj;
        float pw = __builtin_amdgcn_exp2f(t2v * LOG2E) * aw;
        float ph = __builtin_amdgcn_exp2f(t3v * LOG2E) * ah;

        // replicate reference FP order: (val)/W * INPUTW
        float x1 = (px - pw * 0.5f) / 76.0f * 608.0f;
        float y1 = (py - ph * 0.5f) / 76.0f * 608.0f;
        float x2 = (px + pw * 0.5f) / 76.0f * 608.0f;
        float y2 = (py + ph * 0.5f) / 76.0f * 608.0f;
        float area2 = (x2 - x1) * (y2 - y1);
        unsigned li = (c / (unsigned)CELLS_PER_IMG - bi0) * 32u;  // 0 or 32
        float best = 0.0f;  // iou >= 0 always
#pragma unroll
        for (int t = 0; t < 8; ++t) {         // this lane's 8 GTs: m = sub + 4t
            float4 gb = sbox[li + sub + 4u * t];
            float area1 = (gb.z - gb.x) * (gb.w - gb.y);
            float ltx = fmaxf(gb.x, x1), lty = fmaxf(gb.y, y1);
            float rbx = fminf(gb.z, x2), rby = fminf(gb.w, y2);
            float inter = fmaxf(rbx - ltx, 0.0f) * fmaxf(rby - lty, 0.0f);
            float iou = inter * __builtin_amdgcn_rcpf(area1 + area2 - inter);
            best = fmaxf(best, iou);
        }
        // 2-step butterfly max within the 4-lane group (exact for non-NaN)
        best = fmaxf(best, __shfl_xor(best, 1));
        best = fmaxf(best, __shfl_xor(best, 2));
        if (sub == 0u) {
            noobj[c] = (best <= 0.5f) ? 1.0f : 0.0f;
            obj[c] = 0.0f;
        }
    }
}

// ---------------------------------------------------------------------------
// Kernel 2: per-GT best-anchor argmax. (unchanged; runs after decode's
// noobj/obj writes — stream order guarantees completion.)
// ---------------------------------------------------------------------------
__global__ void assign_kernel(const float* __restrict__ gt,
                              float* __restrict__ noobj, float* __restrict__ obj) {
    int r = blockIdx.x * blockDim.x + threadIdx.x;
    if (r >= BB * MM) return;
    const float* g = gt + (size_t)r * 6;
    float cx = g[1], cy = g[2], gw = g[3], gh = g[4];
    float gx1 = (cx - gw * 0.5f) * 608.0f, gy1 = (cy - gh * 0.5f) * 608.0f;
    float gx2 = (cx + gw * 0.5f) * 608.0f, gy2 = (cy + gh * 0.5f) * 608.0f;
    float area_g = (gx2 - gx1) * (gy2 - gy1);
    int best = 0;
    float bestv = -1.0f;
#pragma unroll
    for (int k = 0; k < 9; ++k) {
        float ow = c_anchor[k][0] / 608.0f, oh = c_anchor[k][1] / 608.0f;
        float ax1 = (cx - ow * 0.5f) * 608.0f, ay1 = (cy - oh * 0.5f) * 608.0f;
        float ax2 = (cx + ow * 0.5f) * 608.0f, ay2 = (cy + oh * 0.5f) * 608.0f;
        float ltx = fmaxf(gx1, ax1), lty = fmaxf(gy1, ay1);
        float rbx = fminf(gx2, ax2), rby = fminf(gy2, ay2);
        float inter = fmaxf(rbx - ltx, 0.0f) * fmaxf(rby - lty, 0.0f);
        float area_a = (ax2 - ax1) * (ay2 - ay1);
        float v = inter / (area_g + area_a - inter);
        if (v > bestv) { bestv = v; best = k; }
    }
    if (best < AA) {
        int b = r / MM;  // reference uses row position, not the gt batch column
        int gi = (int)(cx * 76.0f);
        int gj = (int)(cy * 76.0f);
        int flat = ((b * AA + best) * WW + gi) * WW + gj;
        obj[flat] = 1.0f;
        noobj[flat] = 0.0f;
    }
}

extern "C" void kernel_launch(void* const* d_in, const int* in_sizes, int n_in,
                              void* d_out, int out_size, void* d_ws, size_t ws_size,
                              hipStream_t stream) {
    const float* pred = (const float*)d_in[0];
    const float* gt   = (const float*)d_in[1];
    float* dec   = (float*)d_out;            // 23,566,080
    float* noobj = dec + NDECODE;            //    277,248
    float* obj   = noobj + NCELLS;           //    277,248
    (void)d_ws; (void)ws_size;               // no scratch needed

    const int nblocks = (N4 + 1023) / 1024;  // 4 float4s/thread, wave-tiled (R9)
    decode_kernel<<<nblocks, 256, 0, stream>>>(
        (const vfloat4*)pred, (vfloat4*)dec, pred, gt, noobj, obj);

    assign_kernel<<<2, 256, 0, stream>>>(gt, noobj, obj);
}